// Round 3
// 221.857 us; speedup vs baseline: 1.0640x; 1.0640x over previous
//
#include <hip/hip_runtime.h>
#include <hip/hip_bf16.h>

typedef float f32x4 __attribute__((ext_vector_type(4)));
typedef short s16x8 __attribute__((ext_vector_type(8)));
typedef unsigned short u16;

#define B_ 2
#define S_ 2048
#define HID 1536
#define NQ_ 24
#define NKV_ 4
#define HD 64
#define NTOK (B_*S_)
#define QKVN ((NQ_+2*NKV_)*HD)   // 2048
#define ROPE_BLOCKS ((NTOK*28*32)/256)   // 14336
#define VT_BLOCKS (B_*NKV_*(S_/64))      // 256

// Compiler-only memory fence (single-wave block: LDS pipe is in-order, no s_barrier
// needed -> avoids the vmcnt(0) drain). Proven R6->R7 on k_attn.
#define LDS_FENCE() asm volatile("" ::: "memory")

__device__ __forceinline__ float bf2f(u16 u) {
  unsigned int x = ((unsigned int)u) << 16;
  float f; __builtin_memcpy(&f, &x, 4); return f;
}
__device__ __forceinline__ u16 f2bf(float f) {
  unsigned int u; __builtin_memcpy(&u, &f, 4);
  u += 0x7fffu + ((u >> 16) & 1u);
  return (u16)(u >> 16);
}
// 4x f32 -> packed bf16x4 via v_cvt_pk_bf16_f32
__device__ __forceinline__ unsigned long long pk4bf(float a, float b, float c, float d) {
  __hip_bfloat162 x = __float22bfloat162_rn(make_float2(a, b));
  __hip_bfloat162 y = __float22bfloat162_rn(make_float2(c, d));
  unsigned int xi, yi;
  __builtin_memcpy(&xi, &x, 4);
  __builtin_memcpy(&yi, &y, 4);
  return (unsigned long long)xi | ((unsigned long long)yi << 32);
}

// ---------------- fused fp32 -> bf16 conversion of both weight matrices ----------------
// Destinations are adjacent in ws, so one grid covers both (saves a launch).
__global__ __launch_bounds__(256) void k_cvt2(const float* __restrict__ s0, int n0q,
                                              const float* __restrict__ s1, int n1q,
                                              u16* __restrict__ dst) {
  int i = blockIdx.x * 256 + threadIdx.x;   // units of 4 elements
  if (i >= n0q + n1q) return;
  const float* src = (i < n0q) ? s0 : s1;
  int j = (i < n0q) ? i : i - n0q;
  f32x4 v = ((const f32x4*)src)[j];
  *(unsigned long long*)(dst + (size_t)i*4) = pk4bf(v[0], v[1], v[2], v[3]);
}

// ---------------- RMSNorm (fused fp32 read -> bf16 write) ----------------
__global__ __launch_bounds__(384) void k_rmsnorm(const float* __restrict__ x,
                                                 const float* __restrict__ g,
                                                 u16* __restrict__ xn) {
  int row = blockIdx.x;
  int t = threadIdx.x;
  f32x4 v = ((const f32x4*)(x + (size_t)row * HID))[t];
  float ss = v[0]*v[0] + v[1]*v[1] + v[2]*v[2] + v[3]*v[3];
#pragma unroll
  for (int off = 1; off < 64; off <<= 1) ss += __shfl_xor(ss, off);
  __shared__ float red[6];
  if ((t & 63) == 0) red[t >> 6] = ss;
  __syncthreads();
  float tot = red[0] + red[1] + red[2] + red[3] + red[4] + red[5];
  float rs = rsqrtf(tot * (1.f/HID) + 1e-6f);
  f32x4 gv = ((const f32x4*)g)[t];
  ((unsigned long long*)(xn + (size_t)row * HID))[t] =
      pk4bf(v[0]*rs*gv[0], v[1]*rs*gv[1], v[2]*rs*gv[2], v[3]*rs*gv[3]);
}

// ---------------- GEMM C[M][N] = A[M][K] @ W[N][K]^T, M fixed = 4096 ----------------
// R8: (a) K unrolled x2 with two LDS buffer pairs -> 32 MFMAs per barrier pair,
// half the vmcnt(0) drains; (b) XCD-aware swizzle: lin&7 = XCD owns a contiguous
// 4-Mtile stripe (A-stripe 1.6MB resident in its 4MB L2), m-inner traversal
// reuses each W-tile 4x.
template <bool F32OUT>
__global__ __launch_bounds__(256) void k_gemm_bt(const u16* __restrict__ A,
                                                 const u16* __restrict__ W,
                                                 void* __restrict__ Cv,
                                                 const float* __restrict__ resid,
                                                 int N, int K) {
  __shared__ __align__(16) u16 As[2][128*32];
  __shared__ __align__(16) u16 Bs[2][128*32];
  int lin = blockIdx.x;
  int xcd = lin & 7, loc = lin >> 3;
  int mloc = loc & 3, nloc = loc >> 2;          // stripe height 4 (32 Mtiles / 8 XCDs)
  int m0 = (xcd*4 + mloc) * 128, n0 = nloc * 128;
  int tid = threadIdx.x;
  int w = tid >> 6, l = tid & 63;
  int wr = w >> 1, wc = w & 1;
  int c = l & 15, g = l >> 4;
  f32x4 acc[4][4] = {};
  const u16* Ag = A + (size_t)(m0 + w*32 + (l>>2))*K + (l&3)*8;
  const u16* Wg = W + (size_t)(n0 + w*32 + (l>>2))*K + (l&3)*8;
  const int woff = w*32*32;
  for (int k0 = 0; k0 < K; k0 += 64) {
#pragma unroll
    for (int hf = 0; hf < 2; hf++) {
      int kk = k0 + hf*32;
      __builtin_amdgcn_global_load_lds((const __attribute__((address_space(1))) void*)(Ag + kk),
                                       (__attribute__((address_space(3))) void*)(As[hf] + woff), 16, 0, 0);
      __builtin_amdgcn_global_load_lds((const __attribute__((address_space(1))) void*)(Ag + kk + (size_t)16*K),
                                       (__attribute__((address_space(3))) void*)(As[hf] + woff + 16*32), 16, 0, 0);
      __builtin_amdgcn_global_load_lds((const __attribute__((address_space(1))) void*)(Wg + kk),
                                       (__attribute__((address_space(3))) void*)(Bs[hf] + woff), 16, 0, 0);
      __builtin_amdgcn_global_load_lds((const __attribute__((address_space(1))) void*)(Wg + kk + (size_t)16*K),
                                       (__attribute__((address_space(3))) void*)(Bs[hf] + woff + 16*32), 16, 0, 0);
    }
    __syncthreads();
#pragma unroll
    for (int hf = 0; hf < 2; hf++) {
      s16x8 af[4], bq[4];
#pragma unroll
      for (int mt = 0; mt < 4; mt++) af[mt] = *(const s16x8*)(As[hf] + (wr*64 + mt*16 + c)*32 + g*8);
#pragma unroll
      for (int nt = 0; nt < 4; nt++) bq[nt] = *(const s16x8*)(Bs[hf] + (wc*64 + nt*16 + c)*32 + g*8);
#pragma unroll
      for (int mt = 0; mt < 4; mt++)
#pragma unroll
        for (int nt = 0; nt < 4; nt++)
          acc[mt][nt] = __builtin_amdgcn_mfma_f32_16x16x32_bf16(af[mt], bq[nt], acc[mt][nt], 0, 0, 0);
    }
    __syncthreads();
  }
#pragma unroll
  for (int mt = 0; mt < 4; mt++)
#pragma unroll
    for (int nt = 0; nt < 4; nt++)
#pragma unroll
      for (int r = 0; r < 4; r++) {
        int m = m0 + wr*64 + mt*16 + g*4 + r;
        int n = n0 + wc*64 + nt*16 + c;
        size_t off = (size_t)m*N + n;
        float vv = acc[mt][nt][r];
        if (F32OUT) {
          ((float*)Cv)[off] = vv + resid[off];
        } else {
          ((u16*)Cv)[off] = f2bf(vv);
        }
      }
}

// ---------------- fused RoPE(q,k) + V transpose (one launch) ----------------
__global__ __launch_bounds__(256) void k_rope_vt(const u16* __restrict__ qkv,
                                                 u16* __restrict__ q,
                                                 u16* __restrict__ k,
                                                 u16* __restrict__ vt,
                                                 const int* __restrict__ spp) {
  __shared__ u16 tile[64][65];
  int bid = blockIdx.x;
  if (bid < ROPE_BLOCKS) {
    int idx = bid * 256 + threadIdx.x;     // (tok*28 + h)*32 + p
    int p = idx & 31;
    int h = (idx >> 5) % 28;
    int tok = idx / 896;
    int s = tok & (S_ - 1);
    int b = tok >> 11;
    float t = (float)(spp[0] + s);
    // 10000^(-p/32) = exp2(-p * log2(10000)/32); avoids the runtime log in powf
    float inv = exp2f((float)p * -0.41524101186f);
    float fr = t * inv;
    float sn, cs;
    sincosf(fr, &sn, &cs);
    int col = (h < NQ_) ? h*64 + 2*p : HID + (h - NQ_)*64 + 2*p;
    unsigned int pr = *(const unsigned int*)(qkv + (size_t)tok*QKVN + col);
    float x1 = bf2f((u16)(pr & 0xffff));
    float x2 = bf2f((u16)(pr >> 16));
    float y1 = x1*cs - x2*sn;
    float y2 = x2*cs + x1*sn;
    unsigned int outp = (unsigned int)f2bf(y1) | ((unsigned int)f2bf(y2) << 16);
    if (h < NQ_) {
      *(unsigned int*)(q + (((size_t)(b*NQ_ + h))*S_ + s)*64 + 2*p) = outp;
    } else {
      *(unsigned int*)(k + (((size_t)(b*NKV_ + (h - NQ_)))*S_ + s)*64 + 2*p) = outp;
    }
  } else {
    int blk = bid - ROPE_BLOCKS;
    int st = blk & 31;
    int hk = (blk >> 5) & 3;
    int b = blk >> 7;
    int s0 = st * 64;
#pragma unroll
    for (int i = 0; i < 16; i++) {
      int ii = threadIdx.x + i*256;
      int r = ii >> 6, cc = ii & 63;
      tile[r][cc] = qkv[((size_t)(b*S_) + s0 + r)*QKVN + (NQ_+NKV_)*64 + hk*64 + cc];
    }
    __syncthreads();
#pragma unroll
    for (int i = 0; i < 16; i++) {
      int ii = threadIdx.x + i*256;
      int d = ii >> 6, s = ii & 63;
      vt[((size_t)(b*NKV_ + hk)*64 + d)*S_ + s0 + s] = tile[s][d];
    }
  }
}

// ---------------- Flash attention, one wave per (b,h,32-query tile) ----------------
// R9: latency-bound fix (was MfmaUtil 5.5 / VALUBusy 20 / HBM 17% at 48us — nothing
// saturated => stalled on K/V loads from L3):
//  (a) XCD swizzle: bid&7 = XCD owns 6 consecutive (b,h) = exactly one (b,hk);
//      its K+V (512KB) stays L2-resident instead of being evicted by the q/ao streams.
//  (b) Deep prefetch: vf(kt) issued at iteration TOP (cover = QK+softmax x2 ~700cy);
//      kf(kt+1) issued right after its last QK use (cover = softmax+PV ~400cy).
//      Both exceed L2-hit latency -> no per-iteration load stall.
//  (c) Per-qt softmax split halves sa liveness (keeps VGPR under the 3-wave cap).
//  (d) s_setprio(1) around MFMA clusters (measured +4-7% on attn-like structures).
__global__ __launch_bounds__(64, 3) void k_attn(const u16* __restrict__ q,
                                                const u16* __restrict__ k,
                                                const u16* __restrict__ vt,
                                                u16* __restrict__ ao,
                                                const int* __restrict__ spp) {
  __shared__ __align__(16) u16 Pt[32*72];
  int lin = blockIdx.x;
  // XCD-aware swizzle (bid&7 = XCD on MI355X): each XCD gets all 64 q-tiles of
  // 6 consecutive heads sharing one (b,hk) K/V pair.
  int xcd = lin & 7, loc = lin >> 3;
  int qb = loc & 63;
  int bh = xcd * 6 + (loc >> 6);   // [0,48)
  int h = bh % NQ_;
  int b = bh / NQ_;
  int q0 = qb * 32;
  int hk = h / (NQ_/NKV_);
  int l = threadIdx.x;
  int c = l & 15, g = l >> 4;
  int sp = spp[0];
  const u16* qptr = q + ((size_t)(b*NQ_ + h))*S_*64;
  const u16* kptr = k + ((size_t)(b*NKV_ + hk))*S_*64;
  const u16* vptr = vt + ((size_t)(b*NKV_ + hk))*64*S_;

  s16x8 qf[2][2];
#pragma unroll
  for (int qt = 0; qt < 2; qt++)
#pragma unroll
    for (int ks = 0; ks < 2; ks++)
      qf[qt][ks] = *(const s16x8*)(qptr + (size_t)(q0 + qt*16 + c)*64 + ks*32 + g*8);

  f32x4 o[4][2] = {};          // o[dt][qt]: O^T accum, row=d col=q
  float m_run[2], l_run[2];
#pragma unroll
  for (int i = 0; i < 2; i++) { m_run[i] = -1e30f; l_run[i] = 0.f; }

  int lo = sp + q0 - 256; if (lo < 0) lo = 0;
  int hi = sp + q0 + 31;  if (hi > S_ - 1) hi = S_ - 1;
  int kt0 = lo >> 6, kt1 = hi >> 6;

  s16x8 kf[4][2];
#pragma unroll
  for (int km = 0; km < 4; km++)
#pragma unroll
    for (int ks = 0; ks < 2; ks++)
      kf[km][ks] = *(const s16x8*)(kptr + (size_t)(kt0*64 + km*16 + c)*64 + ks*32 + g*8);

  for (int kt = kt0; kt <= kt1; kt++) {
    // V(kt) issued first: consumed at PV, covered by QK x2 + kf prefetch + softmax x2.
    s16x8 vf[2][4];
#pragma unroll
    for (int ks = 0; ks < 2; ks++)
#pragma unroll
      for (int dt = 0; dt < 4; dt++)
        vf[ks][dt] = *(const s16x8*)(vptr + (size_t)(dt*16 + c)*S_ + kt*64 + ks*32 + g*8);

    bool full = (kt*64 + 63 <= sp + q0) && (kt*64 >= sp + q0 - 225);
#pragma unroll
    for (int qt = 0; qt < 2; qt++) {
      f32x4 sa[4];               // S^T slice for this qt: row=key col=query
      __builtin_amdgcn_s_setprio(1);
#pragma unroll
      for (int km = 0; km < 4; km++) {
        f32x4 z = {};
        z = __builtin_amdgcn_mfma_f32_16x16x32_bf16(kf[km][0], qf[qt][0], z, 0, 0, 0);
        sa[km] = __builtin_amdgcn_mfma_f32_16x16x32_bf16(kf[km][1], qf[qt][1], z, 0, 0, 0);
      }
      __builtin_amdgcn_s_setprio(0);
      if (qt == 1 && kt < kt1) {
        // K(kt+1) prefetch right after kf's last use; covered by softmax + PV.
#pragma unroll
        for (int km = 0; km < 4; km++)
#pragma unroll
          for (int ks = 0; ks < 2; ks++)
            kf[km][ks] = *(const s16x8*)(kptr + (size_t)((kt+1)*64 + km*16 + c)*64 + ks*32 + g*8);
      }
      float mx = -1e30f;
      if (full) {
#pragma unroll
        for (int km = 0; km < 4; km++)
#pragma unroll
          for (int r = 0; r < 4; r++) {
            float sv = sa[km][r] * 0.125f;
            sa[km][r] = sv;
            mx = fmaxf(mx, sv);
          }
      } else {
        int pos = sp + q0 + qt*16 + c;
#pragma unroll
        for (int km = 0; km < 4; km++)
#pragma unroll
          for (int r = 0; r < 4; r++) {
            int key = kt*64 + km*16 + g*4 + r;
            float sv = sa[km][r] * 0.125f;
            sv = ((unsigned)(pos - key) <= 256u) ? sv : -1e30f;
            sa[km][r] = sv;
            mx = fmaxf(mx, sv);
          }
      }
      mx = fmaxf(mx, __shfl_xor(mx, 16));
      mx = fmaxf(mx, __shfl_xor(mx, 32));
      float mnew = fmaxf(m_run[qt], mx);
      float alpha = __expf(m_run[qt] - mnew);
      m_run[qt] = mnew;
      float rsum = 0.f;
#pragma unroll
      for (int km = 0; km < 4; km++) {
        float p0 = __expf(sa[km][0] - mnew);   // masked -1e30 underflows to 0
        float p1 = __expf(sa[km][1] - mnew);
        float p2 = __expf(sa[km][2] - mnew);
        float p3 = __expf(sa[km][3] - mnew);
        rsum += p0 + p1 + p2 + p3;
        *(unsigned long long*)(Pt + (qt*16 + c)*72 + km*16 + g*4) = pk4bf(p0, p1, p2, p3);
      }
      rsum += __shfl_xor(rsum, 16);
      rsum += __shfl_xor(rsum, 32);
      l_run[qt] = l_run[qt]*alpha + rsum;
#pragma unroll
      for (int dt = 0; dt < 4; dt++) {
        o[dt][qt][0] *= alpha; o[dt][qt][1] *= alpha;
        o[dt][qt][2] *= alpha; o[dt][qt][3] *= alpha;
      }
    }
    LDS_FENCE();   // Pt writes ordered before reads (in-order DS pipe, same wave)
    // PV: O^T += V^T @ P^T
    __builtin_amdgcn_s_setprio(1);
#pragma unroll
    for (int ks = 0; ks < 2; ks++)
#pragma unroll
      for (int qt = 0; qt < 2; qt++) {
        s16x8 pf = *(const s16x8*)(Pt + (qt*16 + c)*72 + ks*32 + g*8);
#pragma unroll
        for (int dt = 0; dt < 4; dt++)
          o[dt][qt] = __builtin_amdgcn_mfma_f32_16x16x32_bf16(vf[ks][dt], pf, o[dt][qt], 0, 0, 0);
      }
    __builtin_amdgcn_s_setprio(0);
    LDS_FENCE();   // Pt reads ordered before next iteration's writes
  }
#pragma unroll
  for (int qt = 0; qt < 2; qt++) {
    float inv = 1.f / l_run[qt];
    int qi = q0 + qt*16 + c;
    u16* row = ao + ((size_t)(b*S_) + qi)*HID + h*64;
#pragma unroll
    for (int dt = 0; dt < 4; dt++)
      *(unsigned long long*)(row + dt*16 + g*4) =
          pk4bf(o[dt][qt][0]*inv, o[dt][qt][1]*inv, o[dt][qt][2]*inv, o[dt][qt][3]*inv);
  }
}

extern "C" void kernel_launch(void* const* d_in, const int* in_sizes, int n_in,
                              void* d_out, int out_size, void* d_ws, size_t ws_size,
                              hipStream_t stream) {
  const float* x_f32    = (const float*)d_in[0];
  const float* g_f32    = (const float*)d_in[1];
  const float* wqkv_f32 = (const float*)d_in[2];
  const float* wout_f32 = (const float*)d_in[3];
  const int*   spp      = (const int*)d_in[4];
  char* ws = (char*)d_ws;
  // workspace layout (bytes), ~57.1 MB total
  u16* wqkvb = (u16*)(ws);                    //  6,291,456
  u16* woutb = (u16*)(ws + 6291456);          //  4,718,592 (contiguous with wqkvb)
  u16* xn    = (u16*)(ws + 11010048);         // 12,582,912
  u16* qkv   = (u16*)(ws + 23592960);         // 16,777,216
  u16* qbuf  = (u16*)(ws + 40370176);         // 12,582,912
  u16* kbuf  = (u16*)(ws + 52953088);         //  2,097,152
  u16* vtb   = (u16*)(ws + 55050240);         //  2,097,152  (end 57,147,392)
  u16* attn  = xn;                            // aliases xn (dead after GEMM1)

  const int nwq4 = QKVN*HID/4, nwo4 = HID*HID/4;
  k_cvt2<<<(nwq4 + nwo4 + 255)/256, 256, 0, stream>>>(wqkv_f32, nwq4, wout_f32, nwo4, wqkvb);
  k_rmsnorm<<<NTOK, 384, 0, stream>>>(x_f32, g_f32, xn);
  k_gemm_bt<false><<<32*(QKVN/128), 256, 0, stream>>>(xn, wqkvb, qkv, nullptr, QKVN, HID);
  k_rope_vt<<<ROPE_BLOCKS + VT_BLOCKS, 256, 0, stream>>>(qkv, qbuf, kbuf, vtb, spp);
  k_attn<<<B_*NQ_*(S_/32), 64, 0, stream>>>(qbuf, kbuf, vtb, attn, spp);
  k_gemm_bt<true><<<32*(HID/128), 256, 0, stream>>>(attn, woutb, d_out, x_f32, HID, HID);
}

// Round 4
// 205.883 us; speedup vs baseline: 1.1466x; 1.0776x over previous
//
#include <hip/hip_runtime.h>
#include <hip/hip_bf16.h>

typedef float f32x4 __attribute__((ext_vector_type(4)));
typedef short s16x8 __attribute__((ext_vector_type(8)));
typedef unsigned short u16;

#define B_ 2
#define S_ 2048
#define HID 1536
#define NQ_ 24
#define NKV_ 4
#define HD 64
#define NTOK (B_*S_)
#define QKVN ((NQ_+2*NKV_)*HD)   // 2048
#define ROPE_BLOCKS ((NTOK*28*32)/256)   // 14336
#define VT_BLOCKS (B_*NKV_*(S_/64))      // 256

// Compiler-only memory fence (single-wave block: LDS pipe is in-order, no s_barrier
// needed -> avoids the vmcnt(0) drain). Proven R6->R7 on k_attn.
#define LDS_FENCE() asm volatile("" ::: "memory")

__device__ __forceinline__ float bf2f(u16 u) {
  unsigned int x = ((unsigned int)u) << 16;
  float f; __builtin_memcpy(&f, &x, 4); return f;
}
__device__ __forceinline__ u16 f2bf(float f) {
  unsigned int u; __builtin_memcpy(&u, &f, 4);
  u += 0x7fffu + ((u >> 16) & 1u);
  return (u16)(u >> 16);
}
// 4x f32 -> packed bf16x4 via v_cvt_pk_bf16_f32
__device__ __forceinline__ unsigned long long pk4bf(float a, float b, float c, float d) {
  __hip_bfloat162 x = __float22bfloat162_rn(make_float2(a, b));
  __hip_bfloat162 y = __float22bfloat162_rn(make_float2(c, d));
  unsigned int xi, yi;
  __builtin_memcpy(&xi, &x, 4);
  __builtin_memcpy(&yi, &y, 4);
  return (unsigned long long)xi | ((unsigned long long)yi << 32);
}

// ---------------- fused fp32 -> bf16 conversion of both weight matrices ----------------
// Destinations are adjacent in ws, so one grid covers both (saves a launch).
__global__ __launch_bounds__(256) void k_cvt2(const float* __restrict__ s0, int n0q,
                                              const float* __restrict__ s1, int n1q,
                                              u16* __restrict__ dst) {
  int i = blockIdx.x * 256 + threadIdx.x;   // units of 4 elements
  if (i >= n0q + n1q) return;
  const float* src = (i < n0q) ? s0 : s1;
  int j = (i < n0q) ? i : i - n0q;
  f32x4 v = ((const f32x4*)src)[j];
  *(unsigned long long*)(dst + (size_t)i*4) = pk4bf(v[0], v[1], v[2], v[3]);
}

// ---------------- RMSNorm (fused fp32 read -> bf16 write) ----------------
__global__ __launch_bounds__(384) void k_rmsnorm(const float* __restrict__ x,
                                                 const float* __restrict__ g,
                                                 u16* __restrict__ xn) {
  int row = blockIdx.x;
  int t = threadIdx.x;
  f32x4 v = ((const f32x4*)(x + (size_t)row * HID))[t];
  float ss = v[0]*v[0] + v[1]*v[1] + v[2]*v[2] + v[3]*v[3];
#pragma unroll
  for (int off = 1; off < 64; off <<= 1) ss += __shfl_xor(ss, off);
  __shared__ float red[6];
  if ((t & 63) == 0) red[t >> 6] = ss;
  __syncthreads();
  float tot = red[0] + red[1] + red[2] + red[3] + red[4] + red[5];
  float rs = rsqrtf(tot * (1.f/HID) + 1e-6f);
  f32x4 gv = ((const f32x4*)g)[t];
  ((unsigned long long*)(xn + (size_t)row * HID))[t] =
      pk4bf(v[0]*rs*gv[0], v[1]*rs*gv[1], v[2]*rs*gv[2], v[3]*rs*gv[3]);
}

// ---------------- GEMM C[M][N] = A[M][K] @ W[N][K]^T, M fixed = 4096 ----------------
// R10: T3-minimum 2-phase pipeline (m230/m248-proven): STAGE(t+1) issued BEFORE
// compute(t), one vmcnt(0)+barrier per K-tile -> global_load_lds latency hides under
// ds_read+MFMA instead of being serially exposed. Plus T2 XOR slot-swizzle
// ([128][64] tile, slot = (l&7)^(l>>3) pre-swizzled at the GLOBAL source per rule 21,
// same XOR on the read side): 8-way bank conflict -> 2-way (free).
// XCD swizzle kept from R8: lin&7 = XCD owns a contiguous 4-Mtile stripe.
template <bool F32OUT>
__global__ __launch_bounds__(256) void k_gemm_bt(const u16* __restrict__ A,
                                                 const u16* __restrict__ W,
                                                 void* __restrict__ Cv,
                                                 const float* __restrict__ resid,
                                                 int N, int K) {
  // Two named buffer pairs (not a [2] array) so alias analysis can prove that
  // staging into buf^1 doesn't touch buf -> no spurious vmcnt before ds_reads.
  __shared__ __align__(16) u16 As0[128*64], Bs0[128*64];
  __shared__ __align__(16) u16 As1[128*64], Bs1[128*64];
  int lin = blockIdx.x;
  int xcd = lin & 7, loc = lin >> 3;
  int mloc = loc & 3, nloc = loc >> 2;          // stripe height 4 (32 Mtiles / 8 XCDs)
  int m0 = (xcd*4 + mloc) * 128, n0 = nloc * 128;
  int tid = threadIdx.x;
  int w = tid >> 6, l = tid & 63;
  int wr = w >> 1, wc = w & 1;
  int c = l & 15, g = l >> 4;
  f32x4 acc[4][4] = {};
  // Staging: wave w owns rows [w*32, w*32+32). Each global_load_lds covers 8 rows
  // (64 lanes x 16B = 1024B = 8 x 128B rows), LDS dest linear (base + lane*16B).
  // Source slot pre-swizzled: physical slot (l&7) holds logical slot (l&7)^(row&7).
  int r8 = l >> 3;                  // row within the 8-row group = (row & 7)
  int sslot = (l & 7) ^ r8;         // swizzled 16B-slot index in the source row
  const u16* Ag = A + (size_t)(m0 + w*32 + r8)*K + sslot*8;
  const u16* Wg = W + (size_t)(n0 + w*32 + r8)*K + sslot*8;

#define STAGE(dA, dB, k0) do {                                                          \
  _Pragma("unroll")                                                                     \
  for (int i = 0; i < 4; i++) {                                                         \
    __builtin_amdgcn_global_load_lds(                                                   \
        (const __attribute__((address_space(1))) void*)(Ag + (size_t)(i*8)*K + (k0)),   \
        (__attribute__((address_space(3))) void*)(dA + (w*32 + i*8)*64), 16, 0, 0);     \
    __builtin_amdgcn_global_load_lds(                                                   \
        (const __attribute__((address_space(1))) void*)(Wg + (size_t)(i*8)*K + (k0)),   \
        (__attribute__((address_space(3))) void*)(dB + (w*32 + i*8)*64), 16, 0, 0);     \
  } } while (0)

  // Read side: row r, k-slice ks*32+g*8 elems -> logical 16B slot j=ks*4+g,
  // physical slot j^(r&7) = j^(c&7). 16 lanes -> 8 distinct slots -> 2-way (free).
#define COMPUTE(sA, sB) do {                                                            \
  _Pragma("unroll")                                                                     \
  for (int ks = 0; ks < 2; ks++) {                                                      \
    s16x8 af[4], bq[4];                                                                 \
    int sl = ((ks*4 + g) ^ (c & 7)) * 8;                                                \
    _Pragma("unroll")                                                                   \
    for (int mt = 0; mt < 4; mt++)                                                      \
      af[mt] = *(const s16x8*)(sA + (wr*64 + mt*16 + c)*64 + sl);                       \
    _Pragma("unroll")                                                                   \
    for (int nt = 0; nt < 4; nt++)                                                      \
      bq[nt] = *(const s16x8*)(sB + (wc*64 + nt*16 + c)*64 + sl);                       \
    _Pragma("unroll")                                                                   \
    for (int mt = 0; mt < 4; mt++)                                                      \
      _Pragma("unroll")                                                                 \
      for (int nt = 0; nt < 4; nt++)                                                    \
        acc[mt][nt] = __builtin_amdgcn_mfma_f32_16x16x32_bf16(af[mt], bq[nt],           \
                                                              acc[mt][nt], 0, 0, 0);    \
  } } while (0)

  const int NT = K >> 6;            // 24 K-tiles of 64
  STAGE(As0, Bs0, 0);
  __syncthreads();
  for (int t = 0; t + 2 < NT; t += 2) {
    STAGE(As1, Bs1, (t+1)*64);      // prefetch t+1: in flight during compute(t)
    COMPUTE(As0, Bs0);
    __syncthreads();                // drains vmcnt(0): t+1 ready, As0 free
    STAGE(As0, Bs0, (t+2)*64);
    COMPUTE(As1, Bs1);
    __syncthreads();
  }
  STAGE(As1, Bs1, (NT-1)*64);
  COMPUTE(As0, Bs0);
  __syncthreads();
  COMPUTE(As1, Bs1);
#undef STAGE
#undef COMPUTE

#pragma unroll
  for (int mt = 0; mt < 4; mt++)
#pragma unroll
    for (int nt = 0; nt < 4; nt++)
#pragma unroll
      for (int r = 0; r < 4; r++) {
        int m = m0 + wr*64 + mt*16 + g*4 + r;
        int n = n0 + wc*64 + nt*16 + c;
        size_t off = (size_t)m*N + n;
        float vv = acc[mt][nt][r];
        if (F32OUT) {
          ((float*)Cv)[off] = vv + resid[off];
        } else {
          ((u16*)Cv)[off] = f2bf(vv);
        }
      }
}

// ---------------- fused RoPE(q,k) + V transpose (one launch) ----------------
__global__ __launch_bounds__(256) void k_rope_vt(const u16* __restrict__ qkv,
                                                 u16* __restrict__ q,
                                                 u16* __restrict__ k,
                                                 u16* __restrict__ vt,
                                                 const int* __restrict__ spp) {
  __shared__ u16 tile[64][65];
  int bid = blockIdx.x;
  if (bid < ROPE_BLOCKS) {
    int idx = bid * 256 + threadIdx.x;     // (tok*28 + h)*32 + p
    int p = idx & 31;
    int h = (idx >> 5) % 28;
    int tok = idx / 896;
    int s = tok & (S_ - 1);
    int b = tok >> 11;
    float t = (float)(spp[0] + s);
    // 10000^(-p/32) = exp2(-p * log2(10000)/32); avoids the runtime log in powf
    float inv = exp2f((float)p * -0.41524101186f);
    float fr = t * inv;
    float sn, cs;
    sincosf(fr, &sn, &cs);
    int col = (h < NQ_) ? h*64 + 2*p : HID + (h - NQ_)*64 + 2*p;
    unsigned int pr = *(const unsigned int*)(qkv + (size_t)tok*QKVN + col);
    float x1 = bf2f((u16)(pr & 0xffff));
    float x2 = bf2f((u16)(pr >> 16));
    float y1 = x1*cs - x2*sn;
    float y2 = x2*cs + x1*sn;
    unsigned int outp = (unsigned int)f2bf(y1) | ((unsigned int)f2bf(y2) << 16);
    if (h < NQ_) {
      *(unsigned int*)(q + (((size_t)(b*NQ_ + h))*S_ + s)*64 + 2*p) = outp;
    } else {
      *(unsigned int*)(k + (((size_t)(b*NKV_ + (h - NQ_)))*S_ + s)*64 + 2*p) = outp;
    }
  } else {
    int blk = bid - ROPE_BLOCKS;
    int st = blk & 31;
    int hk = (blk >> 5) & 3;
    int b = blk >> 7;
    int s0 = st * 64;
#pragma unroll
    for (int i = 0; i < 16; i++) {
      int ii = threadIdx.x + i*256;
      int r = ii >> 6, cc = ii & 63;
      tile[r][cc] = qkv[((size_t)(b*S_) + s0 + r)*QKVN + (NQ_+NKV_)*64 + hk*64 + cc];
    }
    __syncthreads();
#pragma unroll
    for (int i = 0; i < 16; i++) {
      int ii = threadIdx.x + i*256;
      int d = ii >> 6, s = ii & 63;
      vt[((size_t)(b*NKV_ + hk)*64 + d)*S_ + s0 + s] = tile[s][d];
    }
  }
}

// ---------------- Flash attention, one wave per (b,h,32-query tile) ----------------
// R9 (verified: k_attn dropped out of the top-5 profile, total -14us):
//  (a) XCD swizzle: bid&7 = XCD owns 6 consecutive (b,h) = exactly one (b,hk);
//      its K+V (512KB) stays L2-resident instead of being evicted by the q/ao streams.
//  (b) Deep prefetch: vf(kt) issued at iteration TOP; kf(kt+1) right after last use.
//  (c) Per-qt softmax split halves sa liveness.
//  (d) s_setprio(1) around MFMA clusters.
__global__ __launch_bounds__(64, 3) void k_attn(const u16* __restrict__ q,
                                                const u16* __restrict__ k,
                                                const u16* __restrict__ vt,
                                                u16* __restrict__ ao,
                                                const int* __restrict__ spp) {
  __shared__ __align__(16) u16 Pt[32*72];
  int lin = blockIdx.x;
  // XCD-aware swizzle (bid&7 = XCD on MI355X): each XCD gets all 64 q-tiles of
  // 6 consecutive heads sharing one (b,hk) K/V pair.
  int xcd = lin & 7, loc = lin >> 3;
  int qb = loc & 63;
  int bh = xcd * 6 + (loc >> 6);   // [0,48)
  int h = bh % NQ_;
  int b = bh / NQ_;
  int q0 = qb * 32;
  int hk = h / (NQ_/NKV_);
  int l = threadIdx.x;
  int c = l & 15, g = l >> 4;
  int sp = spp[0];
  const u16* qptr = q + ((size_t)(b*NQ_ + h))*S_*64;
  const u16* kptr = k + ((size_t)(b*NKV_ + hk))*S_*64;
  const u16* vptr = vt + ((size_t)(b*NKV_ + hk))*64*S_;

  s16x8 qf[2][2];
#pragma unroll
  for (int qt = 0; qt < 2; qt++)
#pragma unroll
    for (int ks = 0; ks < 2; ks++)
      qf[qt][ks] = *(const s16x8*)(qptr + (size_t)(q0 + qt*16 + c)*64 + ks*32 + g*8);

  f32x4 o[4][2] = {};          // o[dt][qt]: O^T accum, row=d col=q
  float m_run[2], l_run[2];
#pragma unroll
  for (int i = 0; i < 2; i++) { m_run[i] = -1e30f; l_run[i] = 0.f; }

  int lo = sp + q0 - 256; if (lo < 0) lo = 0;
  int hi = sp + q0 + 31;  if (hi > S_ - 1) hi = S_ - 1;
  int kt0 = lo >> 6, kt1 = hi >> 6;

  s16x8 kf[4][2];
#pragma unroll
  for (int km = 0; km < 4; km++)
#pragma unroll
    for (int ks = 0; ks < 2; ks++)
      kf[km][ks] = *(const s16x8*)(kptr + (size_t)(kt0*64 + km*16 + c)*64 + ks*32 + g*8);

  for (int kt = kt0; kt <= kt1; kt++) {
    // V(kt) issued first: consumed at PV, covered by QK x2 + kf prefetch + softmax x2.
    s16x8 vf[2][4];
#pragma unroll
    for (int ks = 0; ks < 2; ks++)
#pragma unroll
      for (int dt = 0; dt < 4; dt++)
        vf[ks][dt] = *(const s16x8*)(vptr + (size_t)(dt*16 + c)*S_ + kt*64 + ks*32 + g*8);

    bool full = (kt*64 + 63 <= sp + q0) && (kt*64 >= sp + q0 - 225);
#pragma unroll
    for (int qt = 0; qt < 2; qt++) {
      f32x4 sa[4];               // S^T slice for this qt: row=key col=query
      __builtin_amdgcn_s_setprio(1);
#pragma unroll
      for (int km = 0; km < 4; km++) {
        f32x4 z = {};
        z = __builtin_amdgcn_mfma_f32_16x16x32_bf16(kf[km][0], qf[qt][0], z, 0, 0, 0);
        sa[km] = __builtin_amdgcn_mfma_f32_16x16x32_bf16(kf[km][1], qf[qt][1], z, 0, 0, 0);
      }
      __builtin_amdgcn_s_setprio(0);
      if (qt == 1 && kt < kt1) {
        // K(kt+1) prefetch right after kf's last use; covered by softmax + PV.
#pragma unroll
        for (int km = 0; km < 4; km++)
#pragma unroll
          for (int ks = 0; ks < 2; ks++)
            kf[km][ks] = *(const s16x8*)(kptr + (size_t)((kt+1)*64 + km*16 + c)*64 + ks*32 + g*8);
      }
      float mx = -1e30f;
      if (full) {
#pragma unroll
        for (int km = 0; km < 4; km++)
#pragma unroll
          for (int r = 0; r < 4; r++) {
            float sv = sa[km][r] * 0.125f;
            sa[km][r] = sv;
            mx = fmaxf(mx, sv);
          }
      } else {
        int pos = sp + q0 + qt*16 + c;
#pragma unroll
        for (int km = 0; km < 4; km++)
#pragma unroll
          for (int r = 0; r < 4; r++) {
            int key = kt*64 + km*16 + g*4 + r;
            float sv = sa[km][r] * 0.125f;
            sv = ((unsigned)(pos - key) <= 256u) ? sv : -1e30f;
            sa[km][r] = sv;
            mx = fmaxf(mx, sv);
          }
      }
      mx = fmaxf(mx, __shfl_xor(mx, 16));
      mx = fmaxf(mx, __shfl_xor(mx, 32));
      float mnew = fmaxf(m_run[qt], mx);
      float alpha = __expf(m_run[qt] - mnew);
      m_run[qt] = mnew;
      float rsum = 0.f;
#pragma unroll
      for (int km = 0; km < 4; km++) {
        float p0 = __expf(sa[km][0] - mnew);   // masked -1e30 underflows to 0
        float p1 = __expf(sa[km][1] - mnew);
        float p2 = __expf(sa[km][2] - mnew);
        float p3 = __expf(sa[km][3] - mnew);
        rsum += p0 + p1 + p2 + p3;
        *(unsigned long long*)(Pt + (qt*16 + c)*72 + km*16 + g*4) = pk4bf(p0, p1, p2, p3);
      }
      rsum += __shfl_xor(rsum, 16);
      rsum += __shfl_xor(rsum, 32);
      l_run[qt] = l_run[qt]*alpha + rsum;
#pragma unroll
      for (int dt = 0; dt < 4; dt++) {
        o[dt][qt][0] *= alpha; o[dt][qt][1] *= alpha;
        o[dt][qt][2] *= alpha; o[dt][qt][3] *= alpha;
      }
    }
    LDS_FENCE();   // Pt writes ordered before reads (in-order DS pipe, same wave)
    // PV: O^T += V^T @ P^T
    __builtin_amdgcn_s_setprio(1);
#pragma unroll
    for (int ks = 0; ks < 2; ks++)
#pragma unroll
      for (int qt = 0; qt < 2; qt++) {
        s16x8 pf = *(const s16x8*)(Pt + (qt*16 + c)*72 + ks*32 + g*8);
#pragma unroll
        for (int dt = 0; dt < 4; dt++)
          o[dt][qt] = __builtin_amdgcn_mfma_f32_16x16x32_bf16(vf[ks][dt], pf, o[dt][qt], 0, 0, 0);
      }
    __builtin_amdgcn_s_setprio(0);
    LDS_FENCE();   // Pt reads ordered before next iteration's writes
  }
#pragma unroll
  for (int qt = 0; qt < 2; qt++) {
    float inv = 1.f / l_run[qt];
    int qi = q0 + qt*16 + c;
    u16* row = ao + ((size_t)(b*S_) + qi)*HID + h*64;
#pragma unroll
    for (int dt = 0; dt < 4; dt++)
      *(unsigned long long*)(row + dt*16 + g*4) =
          pk4bf(o[dt][qt][0]*inv, o[dt][qt][1]*inv, o[dt][qt][2]*inv, o[dt][qt][3]*inv);
  }
}

extern "C" void kernel_launch(void* const* d_in, const int* in_sizes, int n_in,
                              void* d_out, int out_size, void* d_ws, size_t ws_size,
                              hipStream_t stream) {
  const float* x_f32    = (const float*)d_in[0];
  const float* g_f32    = (const float*)d_in[1];
  const float* wqkv_f32 = (const float*)d_in[2];
  const float* wout_f32 = (const float*)d_in[3];
  const int*   spp      = (const int*)d_in[4];
  char* ws = (char*)d_ws;
  // workspace layout (bytes), ~57.1 MB total
  u16* wqkvb = (u16*)(ws);                    //  6,291,456
  u16* woutb = (u16*)(ws + 6291456);          //  4,718,592 (contiguous with wqkvb)
  u16* xn    = (u16*)(ws + 11010048);         // 12,582,912
  u16* qkv   = (u16*)(ws + 23592960);         // 16,777,216
  u16* qbuf  = (u16*)(ws + 40370176);         // 12,582,912
  u16* kbuf  = (u16*)(ws + 52953088);         //  2,097,152
  u16* vtb   = (u16*)(ws + 55050240);         //  2,097,152  (end 57,147,392)
  u16* attn  = xn;                            // aliases xn (dead after GEMM1)

  const int nwq4 = QKVN*HID/4, nwo4 = HID*HID/4;
  k_cvt2<<<(nwq4 + nwo4 + 255)/256, 256, 0, stream>>>(wqkv_f32, nwq4, wout_f32, nwo4, wqkvb);
  k_rmsnorm<<<NTOK, 384, 0, stream>>>(x_f32, g_f32, xn);
  k_gemm_bt<false><<<32*(QKVN/128), 256, 0, stream>>>(xn, wqkvb, qkv, nullptr, QKVN, HID);
  k_rope_vt<<<ROPE_BLOCKS + VT_BLOCKS, 256, 0, stream>>>(qkv, qbuf, kbuf, vtb, spp);
  k_attn<<<B_*NQ_*(S_/32), 64, 0, stream>>>(qbuf, kbuf, vtb, attn, spp);
  k_gemm_bt<true><<<32*(HID/128), 256, 0, stream>>>(attn, woutb, d_out, x_f32, HID, HID);
}